// Round 2
// baseline (220.279 us; speedup 1.0000x reference)
//
#include <hip/hip_runtime.h>

// Problem constants (from reference): x is (N, T, F) float32.
constexpr int N  = 64;
constexpr int T  = 2048;
constexpr int F  = 256;
constexpr int F4   = F / 4;        // 64 float4 per row  (2^6)
constexpr int ROW4 = T * F4;       // float4 per batch   (2^17)
constexpr int TOTAL4 = N * ROW4;   // 8,388,608 float4 total (2^23)

// One wave (64 lanes) == one (n,t) row of 64 float4s -> `valid` is
// wave-uniform, loads/stores perfectly coalesced at 16 B/lane.
__global__ void __launch_bounds__(256)
chunk_by_slices_kernel(const float4* __restrict__ x4,
                       const int*    __restrict__ slices,   // (N,2) int32
                       const int*    __restrict__ lens,     // (N,)  int32
                       float4*       __restrict__ out4,     // (N,T,F) as float4
                       float*        __restrict__ out_lens) // (N,) as float32
{
    const int tid0   = blockIdx.x * blockDim.x + threadIdx.x;
    const int stride = gridDim.x * blockDim.x;

    // Output 1: chunk_lens = clip(end - start, 0), written as float32.
    if (tid0 < N) {
        const int s = slices[2 * tid0];
        const int e = slices[2 * tid0 + 1];
        int cl = e - s;
        if (cl < 0) cl = 0;
        out_lens[tid0] = (float)cl;
    }

    for (int i = tid0; i < TOTAL4; i += stride) {
        const int n  = i >> 17;          // / ROW4
        const int t  = (i >> 6) & (T - 1);
        const int f4 = i & (F4 - 1);

        // Tiny per-row params; L1/L2-cached broadcasts.
        const int s = slices[2 * n];
        const int e = slices[2 * n + 1];
        const int L = lens[n];

        const int  cl    = e - s;
        const bool empty = (cl <= 0);
        int lp = -s; if (lp < 0) lp = 0; if (empty) lp = 0;   // left_pad
        int s_ = s;  if (s_ < 0) s_ = 0;                      // clip(start, 0)
        int e_ = (e < L) ? e : L;                             // min(end, lens)
        int sl = e_ - s_; if (sl < 0) sl = 0;                 // slice_lens

        const bool valid = (t >= lp) && (t < lp + sl);

        float4 v = make_float4(0.f, 0.f, 0.f, 0.f);
        if (valid) {
            int src = s_ + t - lp;
            src = (src < 0) ? 0 : ((src > T - 1) ? T - 1 : src);  // clip (ref semantics)
            v = x4[n * ROW4 + src * F4 + f4];
        }
        out4[i] = v;
    }
}

extern "C" void kernel_launch(void* const* d_in, const int* in_sizes, int n_in,
                              void* d_out, int out_size, void* d_ws, size_t ws_size,
                              hipStream_t stream) {
    const float4* x4     = (const float4*)d_in[0];
    const int*    slices = (const int*)d_in[1];
    const int*    lens   = (const int*)d_in[2];

    float* out      = (float*)d_out;
    float4* out4    = (float4*)out;
    float* out_lens = out + (size_t)N * T * F;   // output 1 follows output 0, flat

    const int threads = 256;
    const int blocks  = 2048;   // grid-stride; memory-bound cap (G11)
    chunk_by_slices_kernel<<<blocks, threads, 0, stream>>>(x4, slices, lens, out4, out_lens);
}

// Round 4
// 219.686 us; speedup vs baseline: 1.0027x; 1.0027x over previous
//
#include <hip/hip_runtime.h>

// Problem constants (from reference): x is (N, T, F) float32.
constexpr int N  = 64;
constexpr int T  = 2048;
constexpr int F  = 256;
constexpr int F4   = F / 4;        // 64 float4 per row  (2^6)
constexpr int ROW4 = T * F4;       // float4 per batch   (2^17)

// Native clang vector: __builtin_nontemporal_* accepts this (not HIP float4).
typedef float floatx4 __attribute__((ext_vector_type(4)));

// Block mapping: blockIdx.x = n*32 + tchunk. Each block owns 64 t-rows of
// batch n. 256 threads = 4 waves; wave w handles row t0+w+4*iter, lane = f4.
// -> per-block params are blockIdx-uniform (scalar regs), `valid` is
// wave-uniform, loads/stores perfectly coalesced 16 B/lane, write-once
// streaming -> nontemporal.
__global__ void __launch_bounds__(256)
chunk_by_slices_kernel(const floatx4* __restrict__ x4,
                       const int*     __restrict__ slices,   // (N,2) int32
                       const int*     __restrict__ lens,     // (N,)  int32
                       floatx4*       __restrict__ out4,     // (N,T,F) as float4
                       float*         __restrict__ out_lens) // (N,) as float32
{
    const int n      = blockIdx.x >> 5;         // / 32
    const int tchunk = blockIdx.x & 31;
    const int t0     = tchunk << 6;             // * 64

    // Block-uniform params -> compiler emits s_loads; computed once.
    const int s = slices[2 * n];
    const int e = slices[2 * n + 1];
    const int L = lens[n];

    const int  cl    = e - s;
    const bool empty = (cl <= 0);
    int lp = -s; if (lp < 0) lp = 0; if (empty) lp = 0;   // left_pad
    int s_ = s;  if (s_ < 0) s_ = 0;                      // clip(start, 0)
    int e_ = (e < L) ? e : L;                             // min(end, lens)
    int sl = e_ - s_; if (sl < 0) sl = 0;                 // slice_lens
    const int vlo = lp;                                   // valid: [vlo, vhi)
    const int vhi = lp + sl;

    // Output 1: chunk_lens = clip(end - start, 0), float32. One lane total.
    if (tchunk == 0 && threadIdx.x == 0) {
        out_lens[n] = (float)(cl < 0 ? 0 : cl);
    }

    const int f4   = threadIdx.x & 63;
    const int wrow = threadIdx.x >> 6;          // 0..3

    const floatx4 zero = (floatx4)0.0f;
    const floatx4* __restrict__ xrow = x4 + (size_t)n * ROW4;
    floatx4* __restrict__ orow       = out4 + (size_t)n * ROW4;

    #pragma unroll 4
    for (int r = 0; r < 16; ++r) {
        const int t = t0 + (r << 2) + wrow;     // this wave's row
        floatx4 v = zero;
        if (t >= vlo && t < vhi) {              // wave-uniform predicate
            int src = s_ + t - lp;
            src = (src < 0) ? 0 : ((src > T - 1) ? T - 1 : src);  // ref clip
            v = __builtin_nontemporal_load(&xrow[src * F4 + f4]);
        }
        __builtin_nontemporal_store(v, &orow[t * F4 + f4]);
    }
}

extern "C" void kernel_launch(void* const* d_in, const int* in_sizes, int n_in,
                              void* d_out, int out_size, void* d_ws, size_t ws_size,
                              hipStream_t stream) {
    const floatx4* x4    = (const floatx4*)d_in[0];
    const int*    slices = (const int*)d_in[1];
    const int*    lens   = (const int*)d_in[2];

    float* out      = (float*)d_out;
    floatx4* out4   = (floatx4*)out;
    float* out_lens = out + (size_t)N * T * F;   // output 1 follows output 0, flat

    const int threads = 256;
    const int blocks  = N * 32;   // 2048: one block per (n, 64-row t-chunk)
    chunk_by_slices_kernel<<<blocks, threads, 0, stream>>>(x4, slices, lens, out4, out_lens);
}

// Round 5
// 219.414 us; speedup vs baseline: 1.0039x; 1.0012x over previous
//
#include <hip/hip_runtime.h>

// Problem constants (from reference): x is (N, T, F) float32.
constexpr int N  = 64;
constexpr int T  = 2048;
constexpr int F  = 256;
constexpr int F4   = F / 4;        // 64 float4 per row  (2^6)
constexpr int ROW4 = T * F4;       // float4 per batch   (2^17)

// Native clang vector: __builtin_nontemporal_* accepts this (not HIP float4).
typedef float floatx4 __attribute__((ext_vector_type(4)));

// Valid-rows-only gather. Zeros are produced by a prior hipMemsetAsync on the
// whole output (runtime fill kernel, measured 6.6 TB/s on this harness).
// blockIdx.x = n*32 + tchunk; block owns t-rows [t0, t0+64) of batch n and
// writes only the intersection with the valid window [vlo, vhi).
__global__ void __launch_bounds__(256)
chunk_gather_kernel(const floatx4* __restrict__ x4,
                    const int*     __restrict__ slices,   // (N,2) int32
                    const int*     __restrict__ lens,     // (N,)  int32
                    floatx4*       __restrict__ out4,     // (N,T,F) as float4
                    float*         __restrict__ out_lens) // (N,) as float32
{
    const int n      = blockIdx.x >> 5;         // / 32
    const int tchunk = blockIdx.x & 31;
    const int t0     = tchunk << 6;             // * 64

    // Block-uniform params (scalar regs).
    const int s = slices[2 * n];
    const int e = slices[2 * n + 1];
    const int L = lens[n];

    const int  cl    = e - s;
    const bool empty = (cl <= 0);
    int lp = -s; if (lp < 0) lp = 0; if (empty) lp = 0;   // left_pad
    int s_ = s;  if (s_ < 0) s_ = 0;                      // clip(start, 0)
    int e_ = (e < L) ? e : L;                             // min(end, lens)
    int sl = e_ - s_; if (sl < 0) sl = 0;                 // slice_lens
    const int vlo = lp;                                   // valid: [vlo, vhi)
    const int vhi = lp + sl;

    // Output 1: chunk_lens = clip(end - start, 0), float32 (memset wrote 0).
    if (tchunk == 0 && threadIdx.x == 0) {
        out_lens[n] = (float)(cl < 0 ? 0 : cl);
    }

    // Intersection of this block's rows with the valid window.
    int a = (t0 > vlo) ? t0 : vlo;
    int b = ((t0 + 64) < vhi) ? (t0 + 64) : vhi;
    if (a >= b) return;                          // nothing valid here

    const int f4   = threadIdx.x & 63;
    const int wrow = threadIdx.x >> 6;           // wave id 0..3

    const floatx4* __restrict__ xrow = x4 + (size_t)n * ROW4;
    floatx4* __restrict__ orow       = out4 + (size_t)n * ROW4;

    for (int t = a + wrow; t < b; t += 4) {      // wave-uniform rows
        int src = s_ + t - lp;
        src = (src < 0) ? 0 : ((src > T - 1) ? T - 1 : src);  // ref clip
        const floatx4 v = __builtin_nontemporal_load(&xrow[src * F4 + f4]);
        __builtin_nontemporal_store(v, &orow[t * F4 + f4]);
    }
}

extern "C" void kernel_launch(void* const* d_in, const int* in_sizes, int n_in,
                              void* d_out, int out_size, void* d_ws, size_t ws_size,
                              hipStream_t stream) {
    const floatx4* x4    = (const floatx4*)d_in[0];
    const int*    slices = (const int*)d_in[1];
    const int*    lens   = (const int*)d_in[2];

    float* out      = (float*)d_out;
    floatx4* out4   = (floatx4*)out;
    float* out_lens = out + (size_t)N * T * F;   // output 1 follows output 0, flat

    // Zero the whole output (chunks pad + lens) via the runtime fill kernel
    // (graph-capturable memset node; measured ~6.6 TB/s on this harness).
    hipMemsetAsync(d_out, 0, (size_t)out_size * sizeof(float), stream);

    const int threads = 256;
    const int blocks  = N * 32;   // one block per (n, 64-row t-chunk)
    chunk_gather_kernel<<<blocks, threads, 0, stream>>>(x4, slices, lens, out4, out_lens);
}